// Round 5
// baseline (374.838 us; speedup 1.0000x reference)
//
#include <hip/hip_runtime.h>

#define S_LEN 4096
#define DMODEL 64
#define QBLK 64
#define KBLK 32
#define VSTR 36              // padded Vt row stride (elements) -> 72B rows
#define NKT (S_LEN / KBLK)   // 128 k-steps

typedef __attribute__((ext_vector_type(8))) short bf16x8;
typedef __attribute__((ext_vector_type(4))) short bf16x4;
typedef __attribute__((ext_vector_type(4))) float f32x4;
typedef __attribute__((ext_vector_type(4))) unsigned short us4;

__device__ __forceinline__ unsigned short f2bf(float f) {
    unsigned int u = __builtin_bit_cast(unsigned int, f);
    u += 0x7FFFu + ((u >> 16) & 1u);   // round-to-nearest-even
    return (unsigned short)(u >> 16);
}

// load 8 consecutive fp32, convert to a bf16x8 fragment
__device__ __forceinline__ bf16x8 cvt8(const float* __restrict__ p) {
    f32x4 a = *(const f32x4*)p;
    f32x4 b = *(const f32x4*)(p + 4);
    bf16x8 r;
    r[0] = (short)f2bf(a[0]); r[1] = (short)f2bf(a[1]);
    r[2] = (short)f2bf(a[2]); r[3] = (short)f2bf(a[3]);
    r[4] = (short)f2bf(b[0]); r[5] = (short)f2bf(b[1]);
    r[6] = (short)f2bf(b[2]); r[7] = (short)f2bf(b[3]);
    return r;
}

__global__ __launch_bounds__(256)
void attn_v5(const float* __restrict__ Q,
             const float* __restrict__ K,
             const float* __restrict__ V,
             const float* __restrict__ M,
             float* __restrict__ O) {
    __shared__ unsigned short vt[2][DMODEL][VSTR];  // V^T tiles (bf16), double buffered

    const int tid  = threadIdx.x;
    const int wave = tid >> 6;
    const int lane = tid & 63;
    const int g    = lane >> 4;   // lane group 0..3
    const int j    = lane & 15;   // M/N index within mfma tile

    const int bid  = blockIdx.x;
    const int b    = bid >> 6;    // batch 0..7
    const int qt   = bid & 63;    // q tile 0..63
    const int qrow = qt * QBLK + wave * 16 + j;   // this lane's q row

    const float* Qb = Q + (size_t)b * S_LEN * DMODEL;
    const float* Kb = K + (size_t)b * S_LEN * DMODEL;
    const float* Vb = V + (size_t)b * S_LEN * DMODEL;

    // Hoisted Q fragments (B operand of K*Q^T): lane (g,j) holds Q[qrow][8g+e (+32)]
    const bf16x8 qf0 = cvt8(Qb + (size_t)qrow * DMODEL + g * 8);
    const bf16x8 qf1 = cvt8(Qb + (size_t)qrow * DMODEL + g * 8 + 32);

    f32x4 acc[4];
    #pragma unroll
    for (int dt = 0; dt < 4; ++dt) acc[dt] = f32x4{0.f, 0.f, 0.f, 0.f};
    float lsum = 0.f;

    // V staging map: key = tid&31, dgroup = tid>>5 (8 dims each); transpose into vt
    const int skey = tid & 31;
    const int sdg  = tid >> 5;

    {   // stage tile kb=0 into buf 0
        bf16x8 v = cvt8(Vb + (size_t)skey * DMODEL + sdg * 8);
        #pragma unroll
        for (int e = 0; e < 4; ++e) {
            vt[0][sdg * 8 + e][skey]     = (unsigned short)v[e];
            vt[0][sdg * 8 + 4 + e][skey] = (unsigned short)v[4 + e];
        }
    }

    const float* mrow = M + (size_t)qrow * S_LEN;

    for (int kt = 0; kt < NKT; ++kt) {
        const int kb  = kt * KBLK;
        const int cur = kt & 1;
        __syncthreads();   // prev-iter staging of vt[cur] is now visible

        // prefetch-stage next V tile into vt[cur^1]
        if (kt + 1 < NKT) {
            bf16x8 v = cvt8(Vb + (size_t)(kb + KBLK + skey) * DMODEL + sdg * 8);
            #pragma unroll
            for (int e = 0; e < 4; ++e) {
                vt[cur ^ 1][sdg * 8 + e][skey]     = (unsigned short)v[e];
                vt[cur ^ 1][sdg * 8 + 4 + e][skey] = (unsigned short)v[4 + e];
            }
        }

        // ---- S^T = K * Q^T : A = K rows (keys), B = Q rows ----
        bf16x8 kf00 = cvt8(Kb + (size_t)(kb + j) * DMODEL + g * 8);
        bf16x8 kf01 = cvt8(Kb + (size_t)(kb + j) * DMODEL + g * 8 + 32);
        bf16x8 kf10 = cvt8(Kb + (size_t)(kb + 16 + j) * DMODEL + g * 8);
        bf16x8 kf11 = cvt8(Kb + (size_t)(kb + 16 + j) * DMODEL + g * 8 + 32);

        f32x4 st0 = {0.f, 0.f, 0.f, 0.f};
        f32x4 st1 = {0.f, 0.f, 0.f, 0.f};
        st0 = __builtin_amdgcn_mfma_f32_16x16x32_bf16(kf00, qf0, st0, 0, 0, 0);
        st0 = __builtin_amdgcn_mfma_f32_16x16x32_bf16(kf01, qf1, st0, 0, 0, 0);
        st1 = __builtin_amdgcn_mfma_f32_16x16x32_bf16(kf10, qf0, st1, 0, 0, 0);
        st1 = __builtin_amdgcn_mfma_f32_16x16x32_bf16(kf11, qf1, st1, 0, 0, 0);
        // st{t}[r] = S_raw^T[kb + 16t + 4g + r][qrow]

        // ---- mask (exact fp32 loads) ----
        f32x4 m0 = *(const f32x4*)(mrow + kb + g * 4);
        f32x4 m1 = *(const f32x4*)(mrow + kb + 16 + g * 4);

        // ---- weights: w = exp(s/8) * mask (ref's max-subtraction cancels) ----
        bf16x8 pf;   // slot e=(t*4+r) holds key 16t+4g+r (matches PV A placement)
        #pragma unroll
        for (int r = 0; r < 4; ++r) {
            float w0 = __expf(st0[r] * 0.125f) * m0[r];
            float w1 = __expf(st1[r] * 0.125f) * m1[r];
            lsum += w0 + w1;
            pf[r]     = (short)f2bf(w0);
            pf[4 + r] = (short)f2bf(w1);
        }

        // ---- O^T += V^T * P : vf slot e holds the SAME key as pf slot e ----
        #pragma unroll
        for (int dt = 0; dt < 4; ++dt) {
            bf16x4 va = *(const bf16x4*)(&vt[cur][dt * 16 + j][g * 4]);       // keys 4g..4g+3
            bf16x4 vb = *(const bf16x4*)(&vt[cur][dt * 16 + j][16 + g * 4]);  // keys 16+4g..+3
            bf16x8 vf;
            vf[0] = va[0]; vf[1] = va[1]; vf[2] = va[2]; vf[3] = va[3];
            vf[4] = vb[0]; vf[5] = vb[1]; vf[6] = vb[2]; vf[7] = vb[3];
            acc[dt] = __builtin_amdgcn_mfma_f32_16x16x32_bf16(vf, pf, acc[dt], 0, 0, 0);
        }
    }

    // ---- epilogue: reduce lsum across lane groups (same q-row), divide, store fp32 ----
    lsum += __shfl_xor(lsum, 16, 64);
    lsum += __shfl_xor(lsum, 32, 64);
    const float inv = 1.0f / lsum;

    float* orow = O + ((size_t)b * S_LEN + qrow) * DMODEL;
    #pragma unroll
    for (int dt = 0; dt < 4; ++dt) {
        f32x4 o;
        #pragma unroll
        for (int r = 0; r < 4; ++r) o[r] = acc[dt][r] * inv;
        *(f32x4*)(orow + dt * 16 + g * 4) = o;   // d = dt*16 + 4g + r
    }
}

extern "C" void kernel_launch(void* const* d_in, const int* in_sizes, int n_in,
                              void* d_out, int out_size, void* d_ws, size_t ws_size,
                              hipStream_t stream) {
    const float* Q = (const float*)d_in[0];
    const float* K = (const float*)d_in[1];
    const float* V = (const float*)d_in[2];
    const float* M = (const float*)d_in[3];
    float* O = (float*)d_out;

    dim3 grid(8 * (S_LEN / QBLK));   // 512 blocks = 2 per CU
    dim3 block(256);
    attn_v5<<<grid, block, 0, stream>>>(Q, K, V, M, O);
}

// Round 6
// 294.907 us; speedup vs baseline: 1.2710x; 1.2710x over previous
//
#include <hip/hip_runtime.h>

#define S_LEN 4096
#define DMODEL 64
#define QBLK 64
#define KBLK 32
#define NKT (S_LEN / KBLK)   // 128 k-steps
#define NELEM ((size_t)8 * S_LEN * DMODEL)   // per-tensor elements (Q/K/V)

typedef __attribute__((ext_vector_type(8))) short bf16x8;
typedef __attribute__((ext_vector_type(4))) float f32x4;
typedef __attribute__((ext_vector_type(4))) unsigned short us4;

__device__ __forceinline__ unsigned short f2bf(float f) {
    unsigned int u = __builtin_bit_cast(unsigned int, f);
    u += 0x7FFFu + ((u >> 16) & 1u);   // round-to-nearest-even
    return (unsigned short)(u >> 16);
}

__device__ __forceinline__ bf16x8 cvt8(const float* __restrict__ p) {
    f32x4 a = *(const f32x4*)p;
    f32x4 b = *(const f32x4*)(p + 4);
    bf16x8 r;
    r[0] = (short)f2bf(a[0]); r[1] = (short)f2bf(a[1]);
    r[2] = (short)f2bf(a[2]); r[3] = (short)f2bf(a[3]);
    r[4] = (short)f2bf(b[0]); r[5] = (short)f2bf(b[1]);
    r[6] = (short)f2bf(b[2]); r[7] = (short)f2bf(b[3]);
    return r;
}

// ---- K: fp32 -> bf16, layout unchanged ----
__global__ __launch_bounds__(256)
void convert_k(const float* __restrict__ src, unsigned short* __restrict__ dst, int n4) {
    int i = blockIdx.x * blockDim.x + threadIdx.x;
    const int stride = gridDim.x * blockDim.x;
    for (; i < n4; i += stride) {
        f32x4 v = ((const f32x4*)src)[i];
        us4 o;
        o[0] = f2bf(v[0]); o[1] = f2bf(v[1]); o[2] = f2bf(v[2]); o[3] = f2bf(v[3]);
        ((us4*)dst)[i] = o;
    }
}

// ---- V: fp32 [b][k][d] -> bf16 Vta[b][d][p(k)], p permutes within 32-key groups so
//      that a contiguous bf16x8 at [d][kb + g*8] holds keys kb + 16*(e>>2)+4g+(e&3) ----
__global__ __launch_bounds__(256)
void convert_v(const float* __restrict__ V, unsigned short* __restrict__ Vta) {
    __shared__ unsigned short lds[64][72];
    const int t  = threadIdx.x;
    const int b  = blockIdx.x >> 6;
    const int k0 = (blockIdx.x & 63) * 64;

    {   // load 64 keys x 64 dims, cvt to bf16 into LDS
        const int kl = t >> 2, dseg = (t & 3) * 16;
        const float* src = V + ((size_t)(b * S_LEN + k0 + kl)) * DMODEL + dseg;
        #pragma unroll
        for (int i = 0; i < 4; ++i) {
            f32x4 v = *(const f32x4*)(src + i * 4);
            lds[kl][dseg + i * 4 + 0] = f2bf(v[0]);
            lds[kl][dseg + i * 4 + 1] = f2bf(v[1]);
            lds[kl][dseg + i * 4 + 2] = f2bf(v[2]);
            lds[kl][dseg + i * 4 + 3] = f2bf(v[3]);
        }
    }
    __syncthreads();
    {   // write transposed+permuted rows
        const int d = t >> 2, sub = t & 3;
        const int grp = sub >> 1;
        unsigned short* dst = Vta + ((size_t)b * DMODEL + d) * S_LEN + k0 + sub * 16;
        us4 o0, o1, o2, o3;
        #pragma unroll
        for (int m = 0; m < 16; ++m) {
            const int q  = (sub & 1) * 16 + m;          // position within 32-group
            const int g  = (q >> 3) & 3, hi = (q >> 2) & 1, r = q & 3;
            const unsigned short val = lds[grp * 32 + 16 * hi + 4 * g + r][d];
            if (m < 4)       o0[m]     = val;
            else if (m < 8)  o1[m - 4] = val;
            else if (m < 12) o2[m - 8] = val;
            else             o3[m - 12] = val;
        }
        *(us4*)(dst)      = o0;
        *(us4*)(dst + 4)  = o1;
        *(us4*)(dst + 8)  = o2;
        *(us4*)(dst + 12) = o3;
    }
}

// ---- main attention: barrier-free, no LDS ----
template <bool WS>
__global__ __launch_bounds__(256)
void attn_v6(const float* __restrict__ Q,
             const float* __restrict__ Kf,
             const float* __restrict__ Vf,
             const unsigned short* __restrict__ Kw,
             const unsigned short* __restrict__ Vta,
             const float* __restrict__ M,
             float* __restrict__ O) {
    const int tid  = threadIdx.x;
    const int wave = tid >> 6;
    const int lane = tid & 63;
    const int g    = lane >> 4;
    const int j    = lane & 15;

    const int bid  = blockIdx.x;
    const int b    = bid & 7;     // batch -> XCD (round-robin dispatch heuristic)
    const int qt   = bid >> 3;    // q tile 0..63
    const int qrow = qt * QBLK + wave * 16 + j;

    const float* Qb = Q + (size_t)b * S_LEN * DMODEL;

    // hoisted Q fragments
    const bf16x8 qf0 = cvt8(Qb + (size_t)qrow * DMODEL + g * 8);
    const bf16x8 qf1 = cvt8(Qb + (size_t)qrow * DMODEL + g * 8 + 32);

    f32x4 acc[4];
    #pragma unroll
    for (int dt = 0; dt < 4; ++dt) acc[dt] = f32x4{0.f, 0.f, 0.f, 0.f};
    float lsum = 0.f;

    const unsigned short* Kb  = Kw  + (size_t)b * S_LEN * DMODEL;
    const unsigned short* Vtb = Vta + (size_t)b * DMODEL * S_LEN;
    const float* Kfb = Kf + (size_t)b * S_LEN * DMODEL;
    const float* Vfb = Vf + (size_t)b * S_LEN * DMODEL;
    const float* mrow = M + (size_t)qrow * S_LEN;

    // scalar-gather key offsets for the fallback path
    int kg[8];
    #pragma unroll
    for (int e = 0; e < 8; ++e) kg[e] = 16 * (e >> 2) + 4 * g + (e & 3);

    #pragma unroll 2
    for (int kt = 0; kt < NKT; ++kt) {
        const int kb = kt * KBLK;

        // ---- K fragments ----
        bf16x8 kf00, kf01, kf10, kf11;
        if (WS) {
            kf00 = *(const bf16x8*)(Kb + (size_t)(kb + j) * DMODEL + g * 8);
            kf01 = *(const bf16x8*)(Kb + (size_t)(kb + j) * DMODEL + g * 8 + 32);
            kf10 = *(const bf16x8*)(Kb + (size_t)(kb + 16 + j) * DMODEL + g * 8);
            kf11 = *(const bf16x8*)(Kb + (size_t)(kb + 16 + j) * DMODEL + g * 8 + 32);
        } else {
            kf00 = cvt8(Kfb + (size_t)(kb + j) * DMODEL + g * 8);
            kf01 = cvt8(Kfb + (size_t)(kb + j) * DMODEL + g * 8 + 32);
            kf10 = cvt8(Kfb + (size_t)(kb + 16 + j) * DMODEL + g * 8);
            kf11 = cvt8(Kfb + (size_t)(kb + 16 + j) * DMODEL + g * 8 + 32);
        }

        // ---- S^T = K * Q^T ----
        f32x4 st0 = {0.f, 0.f, 0.f, 0.f};
        f32x4 st1 = {0.f, 0.f, 0.f, 0.f};
        st0 = __builtin_amdgcn_mfma_f32_16x16x32_bf16(kf00, qf0, st0, 0, 0, 0);
        st0 = __builtin_amdgcn_mfma_f32_16x16x32_bf16(kf01, qf1, st0, 0, 0, 0);
        st1 = __builtin_amdgcn_mfma_f32_16x16x32_bf16(kf10, qf0, st1, 0, 0, 0);
        st1 = __builtin_amdgcn_mfma_f32_16x16x32_bf16(kf11, qf1, st1, 0, 0, 0);
        // st0[r]: key kb+4g+r, st1[r]: key kb+16+4g+r, column q = qrow

        // ---- mask (exact fp32) ----
        f32x4 m0 = *(const f32x4*)(mrow + kb + g * 4);
        f32x4 m1 = *(const f32x4*)(mrow + kb + 16 + g * 4);

        // ---- weights ----
        bf16x8 pf;   // slot e holds key kb + 16*(e>>2) + 4g + (e&3)
        #pragma unroll
        for (int r = 0; r < 4; ++r) {
            float w0 = __expf(st0[r] * 0.125f) * m0[r];
            float w1 = __expf(st1[r] * 0.125f) * m1[r];
            lsum += w0 + w1;
            pf[r]     = (short)f2bf(w0);
            pf[4 + r] = (short)f2bf(w1);
        }

        // ---- O^T += V^T * P ----
        #pragma unroll
        for (int dt = 0; dt < 4; ++dt) {
            bf16x8 vf;
            if (WS) {
                // contiguous: slots e hold keys kb+16*(e>>2)+4g+(e&3) by Vta construction
                vf = *(const bf16x8*)(Vtb + (size_t)(dt * 16 + j) * S_LEN + kb + g * 8);
            } else {
                #pragma unroll
                for (int e = 0; e < 8; ++e)
                    vf[e] = (short)f2bf(Vfb[(size_t)(kb + kg[e]) * DMODEL + dt * 16 + j]);
            }
            acc[dt] = __builtin_amdgcn_mfma_f32_16x16x32_bf16(vf, pf, acc[dt], 0, 0, 0);
        }
    }

    // ---- epilogue ----
    lsum += __shfl_xor(lsum, 16, 64);
    lsum += __shfl_xor(lsum, 32, 64);
    const float inv = 1.0f / lsum;

    float* orow = O + ((size_t)b * S_LEN + qrow) * DMODEL;
    #pragma unroll
    for (int dt = 0; dt < 4; ++dt) {
        f32x4 o;
        #pragma unroll
        for (int r = 0; r < 4; ++r) o[r] = acc[dt][r] * inv;
        *(f32x4*)(orow + dt * 16 + g * 4) = o;
    }
}

extern "C" void kernel_launch(void* const* d_in, const int* in_sizes, int n_in,
                              void* d_out, int out_size, void* d_ws, size_t ws_size,
                              hipStream_t stream) {
    const float* Q = (const float*)d_in[0];
    const float* K = (const float*)d_in[1];
    const float* V = (const float*)d_in[2];
    const float* M = (const float*)d_in[3];
    float* O = (float*)d_out;

    const size_t bytes_k = NELEM * sizeof(unsigned short);   // 4 MB
    const size_t need = 2 * bytes_k;                         // K + Vta

    if (ws_size >= need) {
        unsigned short* Kw  = (unsigned short*)d_ws;
        unsigned short* Vta = Kw + NELEM;
        convert_k<<<1024, 256, 0, stream>>>(K, Kw, (int)(NELEM / 4));
        convert_v<<<512, 256, 0, stream>>>(V, Vta);
        attn_v6<true><<<512, 256, 0, stream>>>(Q, K, V, Kw, Vta, M, O);
    } else {
        attn_v6<false><<<512, 256, 0, stream>>>(Q, K, V, nullptr, nullptr, M, O);
    }
}